// Round 1
// baseline (369.579 us; speedup 1.0000x reference)
//
#include <hip/hip_runtime.h>
#include <math.h>

#define NB 8
#define NL 4096
#define ND 2048
#define NE 8
#define KTOP 2
#define NR 8
#define ALPHA 0.125f
#define LN_EPS 1e-5f

// ---------------- k1: partial sums of x over L chunks -> partial[split][B][D]
__global__ __launch_bounds__(256) void k1_partial_mean(const float* __restrict__ x,
                                                       float* __restrict__ partial,
                                                       int lchunk) {
    int bid = blockIdx.x;
    int half = bid & 1;          // which 1024-wide d half
    int b = (bid >> 1) & (NB - 1);
    int s = bid >> 4;            // L-chunk index
    int d4 = half * 1024 + threadIdx.x * 4;
    const float* xp = x + ((size_t)(b * NL + s * lchunk)) * ND + d4;
    float4 acc = make_float4(0.f, 0.f, 0.f, 0.f);
    for (int i = 0; i < lchunk; ++i) {
        float4 v = *(const float4*)(xp + (size_t)i * ND);
        acc.x += v.x; acc.y += v.y; acc.z += v.z; acc.w += v.w;
    }
    *(float4*)(partial + ((size_t)s * NB + b) * ND + d4) = acc;
}

// ---------------- k2: h, router, LoRA delta (one block per b)
__global__ __launch_bounds__(256) void k2_router(const float* __restrict__ partial,
                                                 const float* __restrict__ gate_w,
                                                 const float* __restrict__ gate_b,
                                                 const float* __restrict__ A,
                                                 const float* __restrict__ Bw,
                                                 float* __restrict__ delta,
                                                 float* __restrict__ logits_out,
                                                 int* __restrict__ idx_out,
                                                 int split) {
    __shared__ float sh_h[ND];
    __shared__ float sh_logits[NE];
    __shared__ float sh_t[KTOP * NR];
    __shared__ float sh_w[KTOP];
    __shared__ int sh_idx[KTOP];
    int b = blockIdx.x;
    int tid = threadIdx.x;

    // reduce partials -> h
    for (int dd = tid; dd < ND; dd += 256) {
        float s = 0.f;
        for (int si = 0; si < split; ++si) s += partial[((size_t)si * NB + b) * ND + dd];
        sh_h[dd] = s * (1.0f / NL);
    }
    __syncthreads();

    // logits: 32 lanes per expert
    {
        int e = tid >> 5, lane32 = tid & 31;
        float p = 0.f;
        for (int d = lane32; d < ND; d += 32) p += gate_w[e * ND + d] * sh_h[d];
        for (int off = 16; off; off >>= 1) p += __shfl_down(p, off);
        if (lane32 == 0) sh_logits[e] = p + gate_b[e];
    }
    __syncthreads();

    // top-2 + softmax weights (lane 0)
    if (tid == 0) {
        float v1 = -1e30f; int e1 = 0;
        for (int e = 0; e < NE; ++e) if (sh_logits[e] > v1) { v1 = sh_logits[e]; e1 = e; }
        float v2 = -1e30f; int e2 = 0;
        for (int e = 0; e < NE; ++e) if (e != e1 && sh_logits[e] > v2) { v2 = sh_logits[e]; e2 = e; }
        float ex = expf(v2 - v1);
        float w1 = 1.0f / (1.0f + ex);
        sh_idx[0] = e1; sh_idx[1] = e2;
        sh_w[0] = w1; sh_w[1] = ex * w1;
        idx_out[b * KTOP] = e1; idx_out[b * KTOP + 1] = e2;
        for (int e = 0; e < NE; ++e) logits_out[b * NE + e] = sh_logits[e];
    }
    __syncthreads();

    // t[k][r] = <h, A[e_k, r, :]> : 16-lane group per (k,r)
    {
        int grp = tid >> 4, lane16 = tid & 15;
        int k = grp >> 3, r = grp & 7;
        int e = sh_idx[k];
        float p = 0.f;
        for (int d = lane16; d < ND; d += 16) p += sh_h[d] * A[((size_t)e * NR + r) * ND + d];
        for (int off = 8; off; off >>= 1) p += __shfl_down(p, off);
        if (lane16 == 0) sh_t[grp] = p;
    }
    __syncthreads();

    // delta[b,d] = alpha * sum_k w_k * sum_r t[k,r]*Bw[e_k,d,r]
    for (int dd = tid; dd < ND; dd += 256) {
        float acc = 0.f;
        for (int k = 0; k < KTOP; ++k) {
            int e = sh_idx[k];
            const float* bw = Bw + ((size_t)e * ND + dd) * NR;
            float s = 0.f;
#pragma unroll
            for (int r = 0; r < NR; ++r) s += sh_t[k * NR + r] * bw[r];
            acc += sh_w[k] * s;
        }
        delta[b * ND + dd] = acc * ALPHA;
    }
}

// ---------------- k3: aux losses (scalar)
__global__ void k3_aux(const float* __restrict__ logits, const int* __restrict__ idxp,
                       float* __restrict__ aux_out) {
    if (threadIdx.x != 0 || blockIdx.x != 0) return;
    float counts[NE];
    for (int e = 0; e < NE; ++e) counts[e] = 0.f;
    for (int i = 0; i < NB * KTOP; ++i) counts[idxp[i]] += 1.f;
    float f[NE], P[NE];
    for (int e = 0; e < NE; ++e) { f[e] = counts[e] * (1.0f / (NB * KTOP)); P[e] = 0.f; }
    float z = 0.f;
    for (int b = 0; b < NB; ++b) {
        const float* lg = logits + b * NE;
        float m = lg[0];
        for (int e = 1; e < NE; ++e) m = fmaxf(m, lg[e]);
        float s = 0.f;
        for (int e = 0; e < NE; ++e) s += expf(lg[e] - m);
        float inv = 1.0f / s;
        for (int e = 0; e < NE; ++e) P[e] += expf(lg[e] - m) * inv;
        float lse = m + logf(s);
        z += lse * lse;
    }
    z *= (1.0f / NB);
    float lb = 0.f;
    for (int e = 0; e < NE; ++e) lb += f[e] * (P[e] * (1.0f / NB));
    lb *= (float)NE;
    float psum = 0.f;
    for (int e = 0; e < NE; ++e) psum += f[e] + 1e-8f;
    float s2 = 0.f;
    for (int e = 0; e < NE; ++e) { float p = (f[e] + 1e-8f) / psum; s2 += p * p; }
    float renyi = logf(s2);
    aux_out[0] = 0.01f * lb + 0.001f * z + 0.01f * renyi;
}

// ---------------- k4: residual + LayerNorm, one block per (b,l) row
__global__ __launch_bounds__(256) void k4_ln(const float* __restrict__ x,
                                             const float* __restrict__ delta,
                                             const float* __restrict__ gamma,
                                             const float* __restrict__ beta,
                                             float* __restrict__ y) {
    int row = blockIdx.x;
    int b = row >> 12;           // row / NL
    size_t base = (size_t)row * ND;
    int tid = threadIdx.x;
    int d0 = tid * 8;

    float4 xa = *(const float4*)(x + base + d0);
    float4 xb = *(const float4*)(x + base + d0 + 4);
    float4 da = *(const float4*)(delta + (size_t)b * ND + d0);
    float4 db = *(const float4*)(delta + (size_t)b * ND + d0 + 4);
    float v[8] = {xa.x + da.x, xa.y + da.y, xa.z + da.z, xa.w + da.w,
                  xb.x + db.x, xb.y + db.y, xb.z + db.z, xb.w + db.w};
    float s = 0.f, ss = 0.f;
#pragma unroll
    for (int j = 0; j < 8; ++j) { s += v[j]; ss += v[j] * v[j]; }
    for (int off = 32; off; off >>= 1) { s += __shfl_down(s, off); ss += __shfl_down(ss, off); }

    __shared__ float red[2][4];
    __shared__ float stats[2];
    int wid = tid >> 6, lane = tid & 63;
    if (lane == 0) { red[0][wid] = s; red[1][wid] = ss; }
    __syncthreads();
    if (tid == 0) {
        float S = red[0][0] + red[0][1] + red[0][2] + red[0][3];
        float SS = red[1][0] + red[1][1] + red[1][2] + red[1][3];
        float mu = S * (1.0f / ND);
        float var = SS * (1.0f / ND) - mu * mu;
        stats[0] = mu;
        stats[1] = rsqrtf(var + LN_EPS);
    }
    __syncthreads();
    float mu = stats[0], rstd = stats[1];

    float4 ga = *(const float4*)(gamma + d0);
    float4 gb = *(const float4*)(gamma + d0 + 4);
    float4 ba = *(const float4*)(beta + d0);
    float4 bb = *(const float4*)(beta + d0 + 4);
    float4 oa, ob;
    oa.x = (v[0] - mu) * rstd * ga.x + ba.x;
    oa.y = (v[1] - mu) * rstd * ga.y + ba.y;
    oa.z = (v[2] - mu) * rstd * ga.z + ba.z;
    oa.w = (v[3] - mu) * rstd * ga.w + ba.w;
    ob.x = (v[4] - mu) * rstd * gb.x + bb.x;
    ob.y = (v[5] - mu) * rstd * gb.y + bb.y;
    ob.z = (v[6] - mu) * rstd * gb.z + bb.z;
    ob.w = (v[7] - mu) * rstd * gb.w + bb.w;
    *(float4*)(y + base + d0) = oa;
    *(float4*)(y + base + d0 + 4) = ob;
}

extern "C" void kernel_launch(void* const* d_in, const int* in_sizes, int n_in,
                              void* d_out, int out_size, void* d_ws, size_t ws_size,
                              hipStream_t stream) {
    const float* x      = (const float*)d_in[0];
    const float* gate_w = (const float*)d_in[1];
    const float* gate_b = (const float*)d_in[2];
    const float* A      = (const float*)d_in[3];
    const float* Bw     = (const float*)d_in[4];
    const float* gamma  = (const float*)d_in[5];
    const float* beta   = (const float*)d_in[6];
    float* y   = (float*)d_out;
    float* aux = y + (size_t)NB * NL * ND;

    // workspace layout: partial[split][B][D] | delta[B][D] | logits[B][E] | idx[B][K]
    size_t fl = ws_size / sizeof(float);
    int split = 64;
    while (split > 1 && ((size_t)split * NB * ND + NB * ND + NB * NE + 64) > fl) split >>= 1;
    float* partial = (float*)d_ws;
    float* delta   = partial + (size_t)split * NB * ND;
    float* logits  = delta + NB * ND;
    int*   idxp    = (int*)(logits + NB * NE);
    int lchunk = NL / split;

    hipLaunchKernelGGL(k1_partial_mean, dim3(split * NB * 2), dim3(256), 0, stream,
                       x, partial, lchunk);
    hipLaunchKernelGGL(k2_router, dim3(NB), dim3(256), 0, stream,
                       partial, gate_w, gate_b, A, Bw, delta, logits, idxp, split);
    hipLaunchKernelGGL(k3_aux, dim3(1), dim3(64), 0, stream, logits, idxp, aux);
    hipLaunchKernelGGL(k4_ln, dim3(NB * NL), dim3(256), 0, stream,
                       x, delta, gamma, beta, y);
}

// Round 2
// 237.578 us; speedup vs baseline: 1.5556x; 1.5556x over previous
//
#include <hip/hip_runtime.h>
#include <math.h>

#define NB 8
#define NL 4096
#define ND 2048
#define NE 8
#define KTOP 2
#define NR 8
#define ALPHA 0.125f
#define LN_EPS 1e-5f
#define SPLIT 64

// ---------------- k1: partial sums of x over L chunks -> partial[split][B][D]
__global__ __launch_bounds__(256) void k1_partial_mean(const float* __restrict__ x,
                                                       float* __restrict__ partial,
                                                       int lchunk) {
    int bid = blockIdx.x;
    int half = bid & 1;          // which 1024-wide d half
    int b = (bid >> 1) & (NB - 1);
    int s = bid >> 4;            // L-chunk index
    int d4 = half * 1024 + threadIdx.x * 4;
    const float* xp = x + ((size_t)(b * NL + s * lchunk)) * ND + d4;
    float4 a0 = make_float4(0.f, 0.f, 0.f, 0.f);
    float4 a1 = make_float4(0.f, 0.f, 0.f, 0.f);
    for (int i = 0; i < lchunk; i += 2) {
        float4 v0 = *(const float4*)(xp + (size_t)i * ND);
        float4 v1 = *(const float4*)(xp + (size_t)(i + 1) * ND);
        a0.x += v0.x; a0.y += v0.y; a0.z += v0.z; a0.w += v0.w;
        a1.x += v1.x; a1.y += v1.y; a1.z += v1.z; a1.w += v1.w;
    }
    float4 acc = make_float4(a0.x + a1.x, a0.y + a1.y, a0.z + a1.z, a0.w + a1.w);
    *(float4*)(partial + ((size_t)s * NB + b) * ND + d4) = acc;
}

// ---------------- k1b: reduce partial over split -> h[B][D] (scaled by 1/NL)
__global__ __launch_bounds__(256) void k1b_reduce(const float* __restrict__ partial,
                                                  float* __restrict__ h) {
    int bd4 = (blockIdx.x * 256 + threadIdx.x) * 4;   // flat over B*D
    const float* p = partial + bd4;
    float4 a0 = make_float4(0.f, 0.f, 0.f, 0.f);
    float4 a1 = make_float4(0.f, 0.f, 0.f, 0.f);
    float4 a2 = make_float4(0.f, 0.f, 0.f, 0.f);
    float4 a3 = make_float4(0.f, 0.f, 0.f, 0.f);
#pragma unroll 4
    for (int si = 0; si < SPLIT; si += 4) {
        float4 v0 = *(const float4*)(p + (size_t)(si + 0) * NB * ND);
        float4 v1 = *(const float4*)(p + (size_t)(si + 1) * NB * ND);
        float4 v2 = *(const float4*)(p + (size_t)(si + 2) * NB * ND);
        float4 v3 = *(const float4*)(p + (size_t)(si + 3) * NB * ND);
        a0.x += v0.x; a0.y += v0.y; a0.z += v0.z; a0.w += v0.w;
        a1.x += v1.x; a1.y += v1.y; a1.z += v1.z; a1.w += v1.w;
        a2.x += v2.x; a2.y += v2.y; a2.z += v2.z; a2.w += v2.w;
        a3.x += v3.x; a3.y += v3.y; a3.z += v3.z; a3.w += v3.w;
    }
    float4 r;
    r.x = ((a0.x + a1.x) + (a2.x + a3.x)) * (1.0f / NL);
    r.y = ((a0.y + a1.y) + (a2.y + a3.y)) * (1.0f / NL);
    r.z = ((a0.z + a1.z) + (a2.z + a3.z)) * (1.0f / NL);
    r.w = ((a0.w + a1.w) + (a2.w + a3.w)) * (1.0f / NL);
    *(float4*)(h + bd4) = r;
}

// ---------------- k2: router + LoRA delta (one block per b)
__global__ __launch_bounds__(256) void k2_router(const float* __restrict__ hbuf,
                                                 const float* __restrict__ gate_w,
                                                 const float* __restrict__ gate_b,
                                                 const float* __restrict__ A,
                                                 const float* __restrict__ Bw,
                                                 float* __restrict__ delta,
                                                 float* __restrict__ logits_out,
                                                 int* __restrict__ idx_out) {
    __shared__ float sh_h[ND];
    __shared__ float sh_logits[NE];
    __shared__ float sh_t[KTOP * NR];
    __shared__ float sh_w[KTOP];
    __shared__ int sh_idx[KTOP];
    int b = blockIdx.x;
    int tid = threadIdx.x;

    // load h into LDS (vectorized)
    {
        int d4 = tid * 8;
        float4 v0 = *(const float4*)(hbuf + (size_t)b * ND + d4);
        float4 v1 = *(const float4*)(hbuf + (size_t)b * ND + d4 + 4);
        *(float4*)(sh_h + d4) = v0;
        *(float4*)(sh_h + d4 + 4) = v1;
    }
    __syncthreads();

    // logits: 32 lanes per expert
    {
        int e = tid >> 5, lane32 = tid & 31;
        float p = 0.f;
        for (int d = lane32; d < ND; d += 32) p += gate_w[e * ND + d] * sh_h[d];
        for (int off = 16; off; off >>= 1) p += __shfl_down(p, off);
        if (lane32 == 0) sh_logits[e] = p + gate_b[e];
    }
    __syncthreads();

    // top-2 + softmax weights (lane 0)
    if (tid == 0) {
        float v1 = -1e30f; int e1 = 0;
        for (int e = 0; e < NE; ++e) if (sh_logits[e] > v1) { v1 = sh_logits[e]; e1 = e; }
        float v2 = -1e30f; int e2 = 0;
        for (int e = 0; e < NE; ++e) if (e != e1 && sh_logits[e] > v2) { v2 = sh_logits[e]; e2 = e; }
        float ex = expf(v2 - v1);
        float w1 = 1.0f / (1.0f + ex);
        sh_idx[0] = e1; sh_idx[1] = e2;
        sh_w[0] = w1; sh_w[1] = ex * w1;
        idx_out[b * KTOP] = e1; idx_out[b * KTOP + 1] = e2;
        for (int e = 0; e < NE; ++e) logits_out[b * NE + e] = sh_logits[e];
    }
    __syncthreads();

    // t[k][r] = <h, A[e_k, r, :]> : 16-lane group per (k,r)
    {
        int grp = tid >> 4, lane16 = tid & 15;
        int k = grp >> 3, r = grp & 7;
        int e = sh_idx[k];
        const float* ap = A + ((size_t)e * NR + r) * ND;
        float p = 0.f;
#pragma unroll 4
        for (int d = lane16; d < ND; d += 16) p += sh_h[d] * ap[d];
        for (int off = 8; off; off >>= 1) p += __shfl_down(p, off);
        if (lane16 == 0) sh_t[grp] = p;
    }
    __syncthreads();

    // delta[b,d] = alpha * sum_k w_k * sum_r t[k,r]*Bw[e_k,d,r]
    for (int dd = tid; dd < ND; dd += 256) {
        float acc = 0.f;
#pragma unroll
        for (int k = 0; k < KTOP; ++k) {
            int e = sh_idx[k];
            const float4* bw = (const float4*)(Bw + ((size_t)e * ND + dd) * NR);
            float4 w0 = bw[0], w1 = bw[1];
            float s = sh_t[k * NR + 0] * w0.x + sh_t[k * NR + 1] * w0.y +
                      sh_t[k * NR + 2] * w0.z + sh_t[k * NR + 3] * w0.w +
                      sh_t[k * NR + 4] * w1.x + sh_t[k * NR + 5] * w1.y +
                      sh_t[k * NR + 6] * w1.z + sh_t[k * NR + 7] * w1.w;
            acc += sh_w[k] * s;
        }
        delta[b * ND + dd] = acc * ALPHA;
    }
}

// ---------------- k3: aux losses (scalar)
__global__ void k3_aux(const float* __restrict__ logits, const int* __restrict__ idxp,
                       float* __restrict__ aux_out) {
    if (threadIdx.x != 0 || blockIdx.x != 0) return;
    float counts[NE];
    for (int e = 0; e < NE; ++e) counts[e] = 0.f;
    for (int i = 0; i < NB * KTOP; ++i) counts[idxp[i]] += 1.f;
    float f[NE], P[NE];
    for (int e = 0; e < NE; ++e) { f[e] = counts[e] * (1.0f / (NB * KTOP)); P[e] = 0.f; }
    float z = 0.f;
    for (int b = 0; b < NB; ++b) {
        const float* lg = logits + b * NE;
        float m = lg[0];
        for (int e = 1; e < NE; ++e) m = fmaxf(m, lg[e]);
        float s = 0.f;
        for (int e = 0; e < NE; ++e) s += expf(lg[e] - m);
        float inv = 1.0f / s;
        for (int e = 0; e < NE; ++e) P[e] += expf(lg[e] - m) * inv;
        float lse = m + logf(s);
        z += lse * lse;
    }
    z *= (1.0f / NB);
    float lb = 0.f;
    for (int e = 0; e < NE; ++e) lb += f[e] * (P[e] * (1.0f / NB));
    lb *= (float)NE;
    float psum = 0.f;
    for (int e = 0; e < NE; ++e) psum += f[e] + 1e-8f;
    float s2 = 0.f;
    for (int e = 0; e < NE; ++e) { float p = (f[e] + 1e-8f) / psum; s2 += p * p; }
    float renyi = logf(s2);
    aux_out[0] = 0.01f * lb + 0.001f * z + 0.01f * renyi;
}

// ---------------- k4: residual + LayerNorm, one block per (b,l) row
__global__ __launch_bounds__(256) void k4_ln(const float* __restrict__ x,
                                             const float* __restrict__ delta,
                                             const float* __restrict__ gamma,
                                             const float* __restrict__ beta,
                                             float* __restrict__ y) {
    int row = blockIdx.x;
    int b = row >> 12;           // row / NL
    size_t base = (size_t)row * ND;
    int tid = threadIdx.x;
    int d0 = tid * 8;

    float4 xa = *(const float4*)(x + base + d0);
    float4 xb = *(const float4*)(x + base + d0 + 4);
    float4 da = *(const float4*)(delta + (size_t)b * ND + d0);
    float4 db = *(const float4*)(delta + (size_t)b * ND + d0 + 4);
    float v[8] = {xa.x + da.x, xa.y + da.y, xa.z + da.z, xa.w + da.w,
                  xb.x + db.x, xb.y + db.y, xb.z + db.z, xb.w + db.w};
    float s = 0.f, ss = 0.f;
#pragma unroll
    for (int j = 0; j < 8; ++j) { s += v[j]; ss += v[j] * v[j]; }
    for (int off = 32; off; off >>= 1) { s += __shfl_down(s, off); ss += __shfl_down(ss, off); }

    __shared__ float red[2][4];
    __shared__ float stats[2];
    int wid = tid >> 6, lane = tid & 63;
    if (lane == 0) { red[0][wid] = s; red[1][wid] = ss; }
    __syncthreads();
    if (tid == 0) {
        float S = red[0][0] + red[0][1] + red[0][2] + red[0][3];
        float SS = red[1][0] + red[1][1] + red[1][2] + red[1][3];
        float mu = S * (1.0f / ND);
        float var = SS * (1.0f / ND) - mu * mu;
        stats[0] = mu;
        stats[1] = rsqrtf(var + LN_EPS);
    }
    __syncthreads();
    float mu = stats[0], rstd = stats[1];

    float4 ga = *(const float4*)(gamma + d0);
    float4 gb = *(const float4*)(gamma + d0 + 4);
    float4 ba = *(const float4*)(beta + d0);
    float4 bb = *(const float4*)(beta + d0 + 4);
    float4 oa, ob;
    oa.x = (v[0] - mu) * rstd * ga.x + ba.x;
    oa.y = (v[1] - mu) * rstd * ga.y + ba.y;
    oa.z = (v[2] - mu) * rstd * ga.z + ba.z;
    oa.w = (v[3] - mu) * rstd * ga.w + ba.w;
    ob.x = (v[4] - mu) * rstd * gb.x + bb.x;
    ob.y = (v[5] - mu) * rstd * gb.y + bb.y;
    ob.z = (v[6] - mu) * rstd * gb.z + bb.z;
    ob.w = (v[7] - mu) * rstd * gb.w + bb.w;
    *(float4*)(y + base + d0) = oa;
    *(float4*)(y + base + d0 + 4) = ob;
}

extern "C" void kernel_launch(void* const* d_in, const int* in_sizes, int n_in,
                              void* d_out, int out_size, void* d_ws, size_t ws_size,
                              hipStream_t stream) {
    const float* x      = (const float*)d_in[0];
    const float* gate_w = (const float*)d_in[1];
    const float* gate_b = (const float*)d_in[2];
    const float* A      = (const float*)d_in[3];
    const float* Bw     = (const float*)d_in[4];
    const float* gamma  = (const float*)d_in[5];
    const float* beta   = (const float*)d_in[6];
    float* y   = (float*)d_out;
    float* aux = y + (size_t)NB * NL * ND;

    // workspace layout: partial[SPLIT][B][D] | h[B][D] | delta[B][D] | logits[B][E] | idx[B][K]
    float* partial = (float*)d_ws;
    float* hbuf    = partial + (size_t)SPLIT * NB * ND;
    float* delta   = hbuf + NB * ND;
    float* logits  = delta + NB * ND;
    int*   idxp    = (int*)(logits + NB * NE);
    int lchunk = NL / SPLIT;

    hipLaunchKernelGGL(k1_partial_mean, dim3(SPLIT * NB * 2), dim3(256), 0, stream,
                       x, partial, lchunk);
    hipLaunchKernelGGL(k1b_reduce, dim3(NB * ND / 1024), dim3(256), 0, stream,
                       partial, hbuf);
    hipLaunchKernelGGL(k2_router, dim3(NB), dim3(256), 0, stream,
                       hbuf, gate_w, gate_b, A, Bw, delta, logits, idxp);
    hipLaunchKernelGGL(k3_aux, dim3(1), dim3(64), 0, stream, logits, idxp, aux);
    hipLaunchKernelGGL(k4_ln, dim3(NB * NL), dim3(256), 0, stream,
                       x, delta, gamma, beta, y);
}

// Round 3
// 155.287 us; speedup vs baseline: 2.3800x; 1.5299x over previous
//
#include <hip/hip_runtime.h>
#include <math.h>

#define NB 8
#define NL 4096
#define ND 2048
#define NE 8
#define KTOP 2
#define NR 8
#define ALPHA 0.125f
#define LN_EPS 1e-5f
#define SPLIT 64

typedef float f32x4 __attribute__((ext_vector_type(4)));

// ---------------- k1: partial sums of x over L chunks -> partial[split][B][D]
__global__ __launch_bounds__(256) void k1_partial_mean(const float* __restrict__ x,
                                                       float* __restrict__ partial,
                                                       int lchunk) {
    int bid = blockIdx.x;
    int half = bid & 1;          // which 1024-wide d half
    int b = (bid >> 1) & (NB - 1);
    int s = bid >> 4;            // L-chunk index
    int d4 = half * 1024 + threadIdx.x * 4;
    const float* xp = x + ((size_t)(b * NL + s * lchunk)) * ND + d4;
    float4 a0 = make_float4(0.f, 0.f, 0.f, 0.f);
    float4 a1 = make_float4(0.f, 0.f, 0.f, 0.f);
    for (int i = 0; i < lchunk; i += 2) {
        float4 v0 = *(const float4*)(xp + (size_t)i * ND);
        float4 v1 = *(const float4*)(xp + (size_t)(i + 1) * ND);
        a0.x += v0.x; a0.y += v0.y; a0.z += v0.z; a0.w += v0.w;
        a1.x += v1.x; a1.y += v1.y; a1.z += v1.z; a1.w += v1.w;
    }
    float4 acc = make_float4(a0.x + a1.x, a0.y + a1.y, a0.z + a1.z, a0.w + a1.w);
    *(float4*)(partial + ((size_t)s * NB + b) * ND + d4) = acc;
}

// ---------------- k1b: reduce partial over split -> h[B][D] (scaled by 1/NL)
__global__ __launch_bounds__(256) void k1b_reduce(const float* __restrict__ partial,
                                                  float* __restrict__ h) {
    int bd4 = (blockIdx.x * 256 + threadIdx.x) * 4;   // flat over B*D
    const float* p = partial + bd4;
    float4 a0 = make_float4(0.f, 0.f, 0.f, 0.f);
    float4 a1 = make_float4(0.f, 0.f, 0.f, 0.f);
    float4 a2 = make_float4(0.f, 0.f, 0.f, 0.f);
    float4 a3 = make_float4(0.f, 0.f, 0.f, 0.f);
#pragma unroll 4
    for (int si = 0; si < SPLIT; si += 4) {
        float4 v0 = *(const float4*)(p + (size_t)(si + 0) * NB * ND);
        float4 v1 = *(const float4*)(p + (size_t)(si + 1) * NB * ND);
        float4 v2 = *(const float4*)(p + (size_t)(si + 2) * NB * ND);
        float4 v3 = *(const float4*)(p + (size_t)(si + 3) * NB * ND);
        a0.x += v0.x; a0.y += v0.y; a0.z += v0.z; a0.w += v0.w;
        a1.x += v1.x; a1.y += v1.y; a1.z += v1.z; a1.w += v1.w;
        a2.x += v2.x; a2.y += v2.y; a2.z += v2.z; a2.w += v2.w;
        a3.x += v3.x; a3.y += v3.y; a3.z += v3.z; a3.w += v3.w;
    }
    float4 r;
    r.x = ((a0.x + a1.x) + (a2.x + a3.x)) * (1.0f / NL);
    r.y = ((a0.y + a1.y) + (a2.y + a3.y)) * (1.0f / NL);
    r.z = ((a0.z + a1.z) + (a2.z + a3.z)) * (1.0f / NL);
    r.w = ((a0.w + a1.w) + (a2.w + a3.w)) * (1.0f / NL);
    *(float4*)(h + bd4) = r;
}

// ---------------- k2: router + LoRA delta (one block per b)
__global__ __launch_bounds__(256) void k2_router(const float* __restrict__ hbuf,
                                                 const float* __restrict__ gate_w,
                                                 const float* __restrict__ gate_b,
                                                 const float* __restrict__ A,
                                                 const float* __restrict__ Bw,
                                                 float* __restrict__ delta,
                                                 float* __restrict__ logits_out,
                                                 int* __restrict__ idx_out) {
    __shared__ float sh_h[ND];
    __shared__ float sh_logits[NE];
    __shared__ float sh_t[KTOP * NR];
    __shared__ float sh_w[KTOP];
    __shared__ int sh_idx[KTOP];
    int b = blockIdx.x;
    int tid = threadIdx.x;

    // load h into LDS (vectorized)
    {
        int d4 = tid * 8;
        float4 v0 = *(const float4*)(hbuf + (size_t)b * ND + d4);
        float4 v1 = *(const float4*)(hbuf + (size_t)b * ND + d4 + 4);
        *(float4*)(sh_h + d4) = v0;
        *(float4*)(sh_h + d4 + 4) = v1;
    }
    __syncthreads();

    // logits: 32 lanes per expert, float4 per lane
    {
        int e = tid >> 5, lane32 = tid & 31;
        const float4* gw = (const float4*)(gate_w + (size_t)e * ND);
        float p = 0.f;
#pragma unroll 4
        for (int d4 = lane32; d4 < ND / 4; d4 += 32) {
            float4 g = gw[d4];
            float4 hv = *(const float4*)(sh_h + d4 * 4);
            p += g.x * hv.x + g.y * hv.y + g.z * hv.z + g.w * hv.w;
        }
        for (int off = 16; off; off >>= 1) p += __shfl_down(p, off);
        if (lane32 == 0) sh_logits[e] = p + gate_b[e];
    }
    __syncthreads();

    // top-2 + softmax weights (lane 0)
    if (tid == 0) {
        float v1 = -1e30f; int e1 = 0;
        for (int e = 0; e < NE; ++e) if (sh_logits[e] > v1) { v1 = sh_logits[e]; e1 = e; }
        float v2 = -1e30f; int e2 = 0;
        for (int e = 0; e < NE; ++e) if (e != e1 && sh_logits[e] > v2) { v2 = sh_logits[e]; e2 = e; }
        float ex = expf(v2 - v1);
        float w1 = 1.0f / (1.0f + ex);
        sh_idx[0] = e1; sh_idx[1] = e2;
        sh_w[0] = w1; sh_w[1] = ex * w1;
        idx_out[b * KTOP] = e1; idx_out[b * KTOP + 1] = e2;
        for (int e = 0; e < NE; ++e) logits_out[b * NE + e] = sh_logits[e];
    }
    __syncthreads();

    // t[k][r] = <h, A[e_k, r, :]> : 16-lane group per (k,r), float4 per lane
    {
        int grp = tid >> 4, lane16 = tid & 15;
        int k = grp >> 3, r = grp & 7;
        int e = sh_idx[k];
        const float4* ap = (const float4*)(A + ((size_t)e * NR + r) * ND);
        float p = 0.f;
#pragma unroll 4
        for (int d4 = lane16; d4 < ND / 4; d4 += 16) {
            float4 av = ap[d4];
            float4 hv = *(const float4*)(sh_h + d4 * 4);
            p += av.x * hv.x + av.y * hv.y + av.z * hv.z + av.w * hv.w;
        }
        for (int off = 8; off; off >>= 1) p += __shfl_down(p, off);
        if (lane16 == 0) sh_t[grp] = p;
    }
    __syncthreads();

    // delta[b,d] = alpha * sum_k w_k * sum_r t[k,r]*Bw[e_k,d,r]
    for (int dd = tid; dd < ND; dd += 256) {
        float acc = 0.f;
#pragma unroll
        for (int k = 0; k < KTOP; ++k) {
            int e = sh_idx[k];
            const float4* bw = (const float4*)(Bw + ((size_t)e * ND + dd) * NR);
            float4 w0 = bw[0], w1 = bw[1];
            float s = sh_t[k * NR + 0] * w0.x + sh_t[k * NR + 1] * w0.y +
                      sh_t[k * NR + 2] * w0.z + sh_t[k * NR + 3] * w0.w +
                      sh_t[k * NR + 4] * w1.x + sh_t[k * NR + 5] * w1.y +
                      sh_t[k * NR + 6] * w1.z + sh_t[k * NR + 7] * w1.w;
            acc += sh_w[k] * s;
        }
        delta[b * ND + dd] = acc * ALPHA;
    }
}

// ---------------- k3: aux losses (scalar)
__global__ void k3_aux(const float* __restrict__ logits, const int* __restrict__ idxp,
                       float* __restrict__ aux_out) {
    if (threadIdx.x != 0 || blockIdx.x != 0) return;
    float counts[NE];
    for (int e = 0; e < NE; ++e) counts[e] = 0.f;
    for (int i = 0; i < NB * KTOP; ++i) counts[idxp[i]] += 1.f;
    float f[NE], P[NE];
    for (int e = 0; e < NE; ++e) { f[e] = counts[e] * (1.0f / (NB * KTOP)); P[e] = 0.f; }
    float z = 0.f;
    for (int b = 0; b < NB; ++b) {
        const float* lg = logits + b * NE;
        float m = lg[0];
        for (int e = 1; e < NE; ++e) m = fmaxf(m, lg[e]);
        float s = 0.f;
        for (int e = 0; e < NE; ++e) s += expf(lg[e] - m);
        float inv = 1.0f / s;
        for (int e = 0; e < NE; ++e) P[e] += expf(lg[e] - m) * inv;
        float lse = m + logf(s);
        z += lse * lse;
    }
    z *= (1.0f / NB);
    float lb = 0.f;
    for (int e = 0; e < NE; ++e) lb += f[e] * (P[e] * (1.0f / NB));
    lb *= (float)NE;
    float psum = 0.f;
    for (int e = 0; e < NE; ++e) psum += f[e] + 1e-8f;
    float s2 = 0.f;
    for (int e = 0; e < NE; ++e) { float p = (f[e] + 1e-8f) / psum; s2 += p * p; }
    float renyi = logf(s2);
    aux_out[0] = 0.01f * lb + 0.001f * z + 0.01f * renyi;
}

// ---------------- k4: residual + LayerNorm, one block per (b,l) row.
// y stores are NON-TEMPORAL: keep x resident in the 256 MiB L3 so the second
// x pass (and k1's read on subsequent graph replays) hits L3 instead of HBM.
__global__ __launch_bounds__(256) void k4_ln(const float* __restrict__ x,
                                             const float* __restrict__ delta,
                                             const float* __restrict__ gamma,
                                             const float* __restrict__ beta,
                                             float* __restrict__ y) {
    int row = blockIdx.x;
    int b = row >> 12;           // row / NL
    size_t base = (size_t)row * ND;
    int tid = threadIdx.x;
    int d0 = tid * 8;

    float4 xa = *(const float4*)(x + base + d0);
    float4 xb = *(const float4*)(x + base + d0 + 4);
    float4 da = *(const float4*)(delta + (size_t)b * ND + d0);
    float4 db = *(const float4*)(delta + (size_t)b * ND + d0 + 4);
    float v[8] = {xa.x + da.x, xa.y + da.y, xa.z + da.z, xa.w + da.w,
                  xb.x + db.x, xb.y + db.y, xb.z + db.z, xb.w + db.w};
    float s = 0.f, ss = 0.f;
#pragma unroll
    for (int j = 0; j < 8; ++j) { s += v[j]; ss += v[j] * v[j]; }
    for (int off = 32; off; off >>= 1) { s += __shfl_down(s, off); ss += __shfl_down(ss, off); }

    __shared__ float red[2][4];
    __shared__ float stats[2];
    int wid = tid >> 6, lane = tid & 63;
    if (lane == 0) { red[0][wid] = s; red[1][wid] = ss; }
    __syncthreads();
    if (tid == 0) {
        float S = red[0][0] + red[0][1] + red[0][2] + red[0][3];
        float SS = red[1][0] + red[1][1] + red[1][2] + red[1][3];
        float mu = S * (1.0f / ND);
        float var = SS * (1.0f / ND) - mu * mu;
        stats[0] = mu;
        stats[1] = rsqrtf(var + LN_EPS);
    }
    __syncthreads();
    float mu = stats[0], rstd = stats[1];

    float4 ga = *(const float4*)(gamma + d0);
    float4 gb = *(const float4*)(gamma + d0 + 4);
    float4 ba = *(const float4*)(beta + d0);
    float4 bb = *(const float4*)(beta + d0 + 4);
    f32x4 oa, ob;
    oa.x = (v[0] - mu) * rstd * ga.x + ba.x;
    oa.y = (v[1] - mu) * rstd * ga.y + ba.y;
    oa.z = (v[2] - mu) * rstd * ga.z + ba.z;
    oa.w = (v[3] - mu) * rstd * ga.w + ba.w;
    ob.x = (v[4] - mu) * rstd * gb.x + bb.x;
    ob.y = (v[5] - mu) * rstd * gb.y + bb.y;
    ob.z = (v[6] - mu) * rstd * gb.z + bb.z;
    ob.w = (v[7] - mu) * rstd * gb.w + bb.w;
    __builtin_nontemporal_store(oa, (f32x4*)(y + base + d0));
    __builtin_nontemporal_store(ob, (f32x4*)(y + base + d0 + 4));
}

extern "C" void kernel_launch(void* const* d_in, const int* in_sizes, int n_in,
                              void* d_out, int out_size, void* d_ws, size_t ws_size,
                              hipStream_t stream) {
    const float* x      = (const float*)d_in[0];
    const float* gate_w = (const float*)d_in[1];
    const float* gate_b = (const float*)d_in[2];
    const float* A      = (const float*)d_in[3];
    const float* Bw     = (const float*)d_in[4];
    const float* gamma  = (const float*)d_in[5];
    const float* beta   = (const float*)d_in[6];
    float* y   = (float*)d_out;
    float* aux = y + (size_t)NB * NL * ND;

    // workspace layout: partial[SPLIT][B][D] | h[B][D] | delta[B][D] | logits[B][E] | idx[B][K]
    float* partial = (float*)d_ws;
    float* hbuf    = partial + (size_t)SPLIT * NB * ND;
    float* delta   = hbuf + NB * ND;
    float* logits  = delta + NB * ND;
    int*   idxp    = (int*)(logits + NB * NE);
    int lchunk = NL / SPLIT;

    hipLaunchKernelGGL(k1_partial_mean, dim3(SPLIT * NB * 2), dim3(256), 0, stream,
                       x, partial, lchunk);
    hipLaunchKernelGGL(k1b_reduce, dim3(NB * ND / 1024), dim3(256), 0, stream,
                       partial, hbuf);
    hipLaunchKernelGGL(k2_router, dim3(NB), dim3(256), 0, stream,
                       hbuf, gate_w, gate_b, A, Bw, delta, logits, idxp);
    hipLaunchKernelGGL(k3_aux, dim3(1), dim3(64), 0, stream, logits, idxp, aux);
    hipLaunchKernelGGL(k4_ln, dim3(NB * NL), dim3(256), 0, stream,
                       x, delta, gamma, beta, y);
}